// Round 4
// baseline (8194.151 us; speedup 1.0000x reference)
//
#include <hip/hip_runtime.h>

// NeuralODE fused persistent kernel v4 (MI355X / gfx950).
// Split-precision: W1/W2 = Whi(f16,VGPR) + Wlo(f16,LDS); activations h,k as
// hi+lo f16 pairs; y0 and dy split too. All GEMMs transposed, f16 MFMA:
//   k = hhi@W2hi + hlo@W2hi + hhi@W2lo ;  U = khi@W1hi + klo@W1hi + khi@W1lo
// 256-thread blocks (4 waves x 16 rows); one shared Wlo copy per block.

typedef _Float16 f16;
typedef _Float16 f16x4 __attribute__((ext_vector_type(4)));
typedef _Float16 f16x8 __attribute__((ext_vector_type(8)));
typedef float    f32x4 __attribute__((ext_vector_type(4)));

#define MFMA(a, b, c) __builtin_amdgcn_mfma_f32_16x16x32_f16((a), (b), (c), 0, 0, 0)

static __device__ __forceinline__ float fast_tanh(float x) {
    // 1 - 2/(1+exp2(2*log2e*x)); x is provably finite; e=inf -> rcp(inf)=0 -> 1.0 (safe)
    float e = __builtin_amdgcn_exp2f(x * 2.885390081777927f);
    float r = __builtin_amdgcn_rcpf(e + 1.0f);
    return __builtin_fmaf(-2.0f, r, 1.0f);
}

__global__ __launch_bounds__(256, 1) void node_fused(
    const float* __restrict__ y0g, const float* __restrict__ tg,
    const float* __restrict__ W1,  const float* __restrict__ b1,
    const float* __restrict__ W2,  const float* __restrict__ b2,
    const float* __restrict__ Wfc, const float* __restrict__ bfc,
    float* __restrict__ out)
{
    // ---- LDS: 155648 B total ----
    __shared__ __align__(16) f16 w1loL[16 * 2 * 64 * 8];   // 32 KB  A-frags of W1lo
    __shared__ __align__(16) f16 w2loL[4 * 8 * 64 * 8];    // 32 KB  A-frags of W2lo
    __shared__ __align__(16) f16 wfcL [2 * 2 * 64 * 8];    // 4 KB   A-frags of Wfc (f16)
    __shared__ __align__(16) f16 hhiB[4 * 16 * 264];       // 33 KB  per-wave h-hi
    __shared__ __align__(16) f16 hloB[4 * 16 * 264];       // 33 KB  per-wave h-lo
    __shared__ __align__(16) f16 khiB[4 * 16 * 72];        // 9 KB   per-wave k-hi
    __shared__ __align__(16) f16 kloB[4 * 16 * 72];        // 9 KB   per-wave k-lo

    const int tid  = (int)threadIdx.x;
    const int wid  = tid >> 6;
    const int lane = tid & 63;
    const int q    = lane >> 4;   // quad 0..3
    const int c    = lane & 15;   // lane-in-16 (row)
    const int R0   = (int)blockIdx.x * 64 + wid * 16;

    f16* __restrict__ hhi = &hhiB[wid * 16 * 264];
    f16* __restrict__ hlo = &hloB[wid * 16 * 264];
    f16* __restrict__ khi = &khiB[wid * 16 * 72];
    f16* __restrict__ klo = &kloB[wid * 16 * 72];

    // ---------------- hi-weight A-fragments in VGPRs ----------------
    // A-layout (16x16x32): lane holds A[m = tile*16 + c][k = ks*32 + q*8 + j]
    f16x8 w1a[16][2];   // W1T hi
#pragma unroll
    for (int jt = 0; jt < 16; ++jt)
#pragma unroll
        for (int ks = 0; ks < 2; ++ks)
#pragma unroll
            for (int j = 0; j < 8; ++j)
                w1a[jt][ks][j] = (f16)W1[(ks * 32 + q * 8 + j) * 256 + jt * 16 + c];

    f16x8 w2a[4][8];    // W2T hi
#pragma unroll
    for (int dt = 0; dt < 4; ++dt)
#pragma unroll
        for (int ks = 0; ks < 8; ++ks)
#pragma unroll
            for (int j = 0; j < 8; ++j)
                w2a[dt][ks][j] = (f16)W2[(ks * 32 + q * 8 + j) * 64 + dt * 16 + c];

    // ---------------- lo-weight A-fragments -> LDS (split across waves) ----------------
    for (int jt = wid * 4; jt < wid * 4 + 4; ++jt)
        for (int ks = 0; ks < 2; ++ks)
            for (int j = 0; j < 8; ++j) {
                float w = W1[(ks * 32 + q * 8 + j) * 256 + jt * 16 + c];
                f16 hi = (f16)w;
                w1loL[((jt * 2 + ks) * 64 + lane) * 8 + j] = (f16)(w - (float)hi);
            }
    {
        int dt = wid;
        for (int ks = 0; ks < 8; ++ks)
            for (int j = 0; j < 8; ++j) {
                float w = W2[(ks * 32 + q * 8 + j) * 64 + dt * 16 + c];
                f16 hi = (f16)w;
                w2loL[((dt * 8 + ks) * 64 + lane) * 8 + j] = (f16)(w - (float)hi);
            }
    }
    if (wid == 0)
        for (int ot = 0; ot < 2; ++ot)
            for (int ks = 0; ks < 2; ++ks)
                for (int j = 0; j < 8; ++j)
                    wfcL[((ot * 2 + ks) * 64 + lane) * 8 + j] =
                        (f16)Wfc[(ks * 32 + q * 8 + j) * 32 + ot * 16 + c];
    __syncthreads();

    // biases to registers
    f32x4 b1v[16], b2v[4], bfcv[2];
#pragma unroll
    for (int jt = 0; jt < 16; ++jt)
#pragma unroll
        for (int r = 0; r < 4; ++r) b1v[jt][r] = b1[jt * 16 + 4 * q + r];
#pragma unroll
    for (int dt = 0; dt < 4; ++dt)
#pragma unroll
        for (int r = 0; r < 4; ++r) b2v[dt][r] = b2[dt * 16 + 4 * q + r];
#pragma unroll
    for (int ot = 0; ot < 2; ++ot)
#pragma unroll
        for (int r = 0; r < 4; ++r) bfcv[ot][r] = bfc[ot * 16 + 4 * q + r];

    // ---------------- init from y0 (split hi+lo) ----------------
    f16x8 y0hi[2], y0lo[2];
#pragma unroll
    for (int ks = 0; ks < 2; ++ks)
#pragma unroll
        for (int j = 0; j < 8; ++j) {
            float v = y0g[(R0 + c) * 64 + ks * 32 + q * 8 + j];
            f16 hi = (f16)v;
            y0hi[ks][j] = hi;
            y0lo[ks][j] = (f16)(v - (float)hi);
        }

    f32x4 P1[16];
#pragma unroll
    for (int jt = 0; jt < 16; ++jt) {
        f32x4 cc = b1v[jt];
#pragma unroll
        for (int ks = 0; ks < 2; ++ks) {
            f16x8 alo = *reinterpret_cast<const f16x8*>(&w1loL[((jt * 2 + ks) * 64 + lane) * 8]);
            cc = MFMA(w1a[jt][ks], y0hi[ks], cc);
            cc = MFMA(w1a[jt][ks], y0lo[ks], cc);
            cc = MFMA(alo,         y0hi[ks], cc);
        }
        P1[jt] = cc;
    }
    f32x4 pfc[2];
#pragma unroll
    for (int ot = 0; ot < 2; ++ot) {
        f32x4 z = {0.f, 0.f, 0.f, 0.f};
#pragma unroll
        for (int ks = 0; ks < 2; ++ks) {
            f16x8 wa = *reinterpret_cast<const f16x8*>(&wfcL[((ot * 2 + ks) * 64 + lane) * 8]);
            z = MFMA(wa, y0hi[ks], z);
            z = MFMA(wa, y0lo[ks], z);
        }
        pfc[ot] = z;
    }
#pragma unroll
    for (int ot = 0; ot < 2; ++ot) {
        f32x4 v = pfc[ot] + bfcv[ot];
        *reinterpret_cast<f32x4*>(&out[(size_t)(R0 + c) * 32 + ot * 16 + 4 * q]) = v;
    }

    f32x4 U[16];
#pragma unroll
    for (int jt = 0; jt < 16; ++jt) U[jt] = f32x4{0.f, 0.f, 0.f, 0.f};
    f32x4 dy[4];
#pragma unroll
    for (int dt = 0; dt < 4; ++dt) dy[dt] = f32x4{0.f, 0.f, 0.f, 0.f};
    f32x4 S[16];

    float hh = 0.f, ch = 0.f, c6 = 0.f;

    auto stage = [&](float carg, float w, bool first) {
        // (1) h = tanh(P1 + carg*U): split hi/lo -> LDS
#pragma unroll
        for (int jt = 0; jt < 16; ++jt) {
            float a0 = P1[jt][0], a1 = P1[jt][1], a2 = P1[jt][2], a3 = P1[jt][3];
            if (!first) {
                a0 = __builtin_fmaf(carg, U[jt][0], a0);
                a1 = __builtin_fmaf(carg, U[jt][1], a1);
                a2 = __builtin_fmaf(carg, U[jt][2], a2);
                a3 = __builtin_fmaf(carg, U[jt][3], a3);
            }
            float t0 = fast_tanh(a0), t1 = fast_tanh(a1), t2 = fast_tanh(a2), t3 = fast_tanh(a3);
            f16x4 hv, lv;
            hv[0] = (f16)t0; hv[1] = (f16)t1; hv[2] = (f16)t2; hv[3] = (f16)t3;
            lv[0] = (f16)(t0 - (float)hv[0]); lv[1] = (f16)(t1 - (float)hv[1]);
            lv[2] = (f16)(t2 - (float)hv[2]); lv[3] = (f16)(t3 - (float)hv[3]);
            *reinterpret_cast<f16x4*>(&hhi[c * 264 + jt * 16 + 4 * q]) = hv;
            *reinterpret_cast<f16x4*>(&hlo[c * 264 + jt * 16 + 4 * q]) = lv;
        }
        __syncthreads();
        // (2) kT = hhi@W2hi + hlo@W2hi + hhi@W2lo + b2
        f32x4 ka[4];
#pragma unroll
        for (int dt = 0; dt < 4; ++dt) ka[dt] = b2v[dt];
#pragma unroll
        for (int ks = 0; ks < 8; ++ks) {
            f16x8 bhi = *reinterpret_cast<const f16x8*>(&hhi[c * 264 + ks * 32 + q * 8]);
            f16x8 blo = *reinterpret_cast<const f16x8*>(&hlo[c * 264 + ks * 32 + q * 8]);
#pragma unroll
            for (int dt = 0; dt < 4; ++dt) {
                f16x8 alo = *reinterpret_cast<const f16x8*>(&w2loL[((dt * 8 + ks) * 64 + lane) * 8]);
                ka[dt] = MFMA(w2a[dt][ks], bhi, ka[dt]);
                ka[dt] = MFMA(w2a[dt][ks], blo, ka[dt]);
                ka[dt] = MFMA(alo,          bhi, ka[dt]);
            }
        }
        // (3) dy += (c6*w)*k ; split k hi/lo -> LDS
        float cw = c6 * w;
#pragma unroll
        for (int dt = 0; dt < 4; ++dt) {
            dy[dt] += ka[dt] * cw;
            f16x4 hv, lv;
            hv[0] = (f16)ka[dt][0]; hv[1] = (f16)ka[dt][1];
            hv[2] = (f16)ka[dt][2]; hv[3] = (f16)ka[dt][3];
            lv[0] = (f16)(ka[dt][0] - (float)hv[0]); lv[1] = (f16)(ka[dt][1] - (float)hv[1]);
            lv[2] = (f16)(ka[dt][2] - (float)hv[2]); lv[3] = (f16)(ka[dt][3] - (float)hv[3]);
            *reinterpret_cast<f16x4*>(&khi[c * 72 + dt * 16 + 4 * q]) = hv;
            *reinterpret_cast<f16x4*>(&klo[c * 72 + dt * 16 + 4 * q]) = lv;
        }
        __syncthreads();
        // (4) UT = khi@W1hi + klo@W1hi + khi@W1lo
        f16x8 kh0 = *reinterpret_cast<const f16x8*>(&khi[c * 72 + q * 8]);
        f16x8 kh1 = *reinterpret_cast<const f16x8*>(&khi[c * 72 + 32 + q * 8]);
        f16x8 kl0 = *reinterpret_cast<const f16x8*>(&klo[c * 72 + q * 8]);
        f16x8 kl1 = *reinterpret_cast<const f16x8*>(&klo[c * 72 + 32 + q * 8]);
#pragma unroll
        for (int jt = 0; jt < 16; ++jt) {
            f16x8 a0 = *reinterpret_cast<const f16x8*>(&w1loL[((jt * 2 + 0) * 64 + lane) * 8]);
            f16x8 a1 = *reinterpret_cast<const f16x8*>(&w1loL[((jt * 2 + 1) * 64 + lane) * 8]);
            f32x4 z = {0.f, 0.f, 0.f, 0.f};
            z = MFMA(w1a[jt][0], kh0, z);
            z = MFMA(w1a[jt][0], kl0, z);
            z = MFMA(a0,         kh0, z);
            z = MFMA(w1a[jt][1], kh1, z);
            z = MFMA(w1a[jt][1], kl1, z);
            z = MFMA(a1,         kh1, z);
            U[jt] = z;
        }
        // (5) S += w * U
#pragma unroll
        for (int jt = 0; jt < 16; ++jt) S[jt] += U[jt] * w;
        __syncthreads();
    };

#pragma unroll 1
    for (int ti = 0; ti < 49; ++ti) {
        float dtv = tg[ti + 1] - tg[ti];
        hh = dtv * 0.125f;
        ch = 0.5f * hh;
        c6 = hh * (1.0f / 6.0f);
#pragma unroll 1
        for (int sub = 0; sub < 8; ++sub) {
#pragma unroll
            for (int jt = 0; jt < 16; ++jt) S[jt] = f32x4{0.f, 0.f, 0.f, 0.f};
            stage(0.0f, 1.0f, true);
            stage(ch,   2.0f, false);
            stage(ch,   2.0f, false);
            stage(hh,   1.0f, false);
#pragma unroll
            for (int jt = 0; jt < 16; ++jt) P1[jt] += S[jt] * c6;
        }
        // ---- interval epilogue: pfc += dy @ Wfc (dy split hi+lo), emit row ----
#pragma unroll
        for (int dt = 0; dt < 4; ++dt) {
            f16x4 hv, lv;
            hv[0] = (f16)dy[dt][0]; hv[1] = (f16)dy[dt][1];
            hv[2] = (f16)dy[dt][2]; hv[3] = (f16)dy[dt][3];
            lv[0] = (f16)(dy[dt][0] - (float)hv[0]); lv[1] = (f16)(dy[dt][1] - (float)hv[1]);
            lv[2] = (f16)(dy[dt][2] - (float)hv[2]); lv[3] = (f16)(dy[dt][3] - (float)hv[3]);
            *reinterpret_cast<f16x4*>(&khi[c * 72 + dt * 16 + 4 * q]) = hv;
            *reinterpret_cast<f16x4*>(&klo[c * 72 + dt * 16 + 4 * q]) = lv;
            dy[dt] = f32x4{0.f, 0.f, 0.f, 0.f};
        }
        __syncthreads();
        {
            f16x8 dh0 = *reinterpret_cast<const f16x8*>(&khi[c * 72 + q * 8]);
            f16x8 dh1 = *reinterpret_cast<const f16x8*>(&khi[c * 72 + 32 + q * 8]);
            f16x8 dl0 = *reinterpret_cast<const f16x8*>(&klo[c * 72 + q * 8]);
            f16x8 dl1 = *reinterpret_cast<const f16x8*>(&klo[c * 72 + 32 + q * 8]);
#pragma unroll
            for (int ot = 0; ot < 2; ++ot) {
                f16x8 wa0 = *reinterpret_cast<const f16x8*>(&wfcL[((ot * 2 + 0) * 64 + lane) * 8]);
                f16x8 wa1 = *reinterpret_cast<const f16x8*>(&wfcL[((ot * 2 + 1) * 64 + lane) * 8]);
                pfc[ot] = MFMA(wa0, dh0, pfc[ot]);
                pfc[ot] = MFMA(wa0, dl0, pfc[ot]);
                pfc[ot] = MFMA(wa1, dh1, pfc[ot]);
                pfc[ot] = MFMA(wa1, dl1, pfc[ot]);
            }
        }
        __syncthreads();
        size_t base = (size_t)(ti + 1) * (16384 * 32);
#pragma unroll
        for (int ot = 0; ot < 2; ++ot) {
            f32x4 v = pfc[ot] + bfcv[ot];
            *reinterpret_cast<f32x4*>(&out[base + (size_t)(R0 + c) * 32 + ot * 16 + 4 * q]) = v;
        }
    }
}

extern "C" void kernel_launch(void* const* d_in, const int* in_sizes, int n_in,
                              void* d_out, int out_size, void* d_ws, size_t ws_size,
                              hipStream_t stream) {
    (void)in_sizes; (void)n_in; (void)d_ws; (void)ws_size; (void)out_size;
    const float* y0  = (const float*)d_in[0];
    const float* t   = (const float*)d_in[1];
    const float* W1  = (const float*)d_in[2];
    const float* b1  = (const float*)d_in[3];
    const float* W2  = (const float*)d_in[4];
    const float* b2  = (const float*)d_in[5];
    const float* Wfc = (const float*)d_in[6];
    const float* bfc = (const float*)d_in[7];
    float* out = (float*)d_out;
    // 256 blocks x 256 threads: 4 waves x 16 rows per block, 1 block/CU (152 KB LDS)
    node_fused<<<dim3(256), dim3(256), 0, stream>>>(y0, t, W1, b1, W2, b2, Wfc, bfc, out);
}

// Round 5
// 7344.908 us; speedup vs baseline: 1.1156x; 1.1156x over previous
//
#include <hip/hip_runtime.h>

// NeuralODE fused persistent kernel v5 (MI355X / gfx950).
// Split-precision: W1/W2 = Whi(f16,VGPR) + Wlo(f16,LDS); activations h,k as
// hi+lo f16 pairs; y0 and dy split too. All GEMMs transposed, f16 MFMA.
// v5: h/k LDS buffers are WAVE-PRIVATE -> replaced per-stage __syncthreads()
// (full s_barrier, lockstepped 4 waves) with wave-local fences:
//   __threadfence_block() (lgkmcnt drain + compiler fence) + wave_barrier().
// Only the init weight-staging barrier remains a real __syncthreads().

typedef _Float16 f16;
typedef _Float16 f16x4 __attribute__((ext_vector_type(4)));
typedef _Float16 f16x8 __attribute__((ext_vector_type(8)));
typedef float    f32x4 __attribute__((ext_vector_type(4)));

#define MFMA(a, b, c) __builtin_amdgcn_mfma_f32_16x16x32_f16((a), (b), (c), 0, 0, 0)

// Wave-local LDS exchange point: drain own DS ops + forbid compiler reordering.
static __device__ __forceinline__ void wave_exchange_fence() {
    __threadfence_block();
    __builtin_amdgcn_wave_barrier();
}

static __device__ __forceinline__ float fast_tanh(float x) {
    // 1 - 2/(1+exp2(2*log2e*x)); e=inf -> rcp(inf)=0 -> 1.0 (safe)
    float e = __builtin_amdgcn_exp2f(x * 2.885390081777927f);
    float r = __builtin_amdgcn_rcpf(e + 1.0f);
    return __builtin_fmaf(-2.0f, r, 1.0f);
}

__global__ __launch_bounds__(256, 1) void node_fused(
    const float* __restrict__ y0g, const float* __restrict__ tg,
    const float* __restrict__ W1,  const float* __restrict__ b1,
    const float* __restrict__ W2,  const float* __restrict__ b2,
    const float* __restrict__ Wfc, const float* __restrict__ bfc,
    float* __restrict__ out)
{
    // ---- LDS: 155648 B total ----
    __shared__ __align__(16) f16 w1loL[16 * 2 * 64 * 8];   // 32 KB  A-frags of W1lo
    __shared__ __align__(16) f16 w2loL[4 * 8 * 64 * 8];    // 32 KB  A-frags of W2lo
    __shared__ __align__(16) f16 wfcL [2 * 2 * 64 * 8];    // 4 KB   A-frags of Wfc (f16)
    __shared__ __align__(16) f16 hhiB[4 * 16 * 264];       // 33 KB  per-wave h-hi
    __shared__ __align__(16) f16 hloB[4 * 16 * 264];       // 33 KB  per-wave h-lo
    __shared__ __align__(16) f16 khiB[4 * 16 * 72];        // 9 KB   per-wave k-hi
    __shared__ __align__(16) f16 kloB[4 * 16 * 72];        // 9 KB   per-wave k-lo

    const int tid  = (int)threadIdx.x;
    const int wid  = tid >> 6;
    const int lane = tid & 63;
    const int q    = lane >> 4;   // quad 0..3
    const int c    = lane & 15;   // lane-in-16 (row)
    const int R0   = (int)blockIdx.x * 64 + wid * 16;

    f16* __restrict__ hhi = &hhiB[wid * 16 * 264];
    f16* __restrict__ hlo = &hloB[wid * 16 * 264];
    f16* __restrict__ khi = &khiB[wid * 16 * 72];
    f16* __restrict__ klo = &kloB[wid * 16 * 72];

    // ---------------- hi-weight A-fragments in VGPRs ----------------
    // A-layout (16x16x32): lane holds A[m = tile*16 + c][k = ks*32 + q*8 + j]
    f16x8 w1a[16][2];   // W1T hi
#pragma unroll
    for (int jt = 0; jt < 16; ++jt)
#pragma unroll
        for (int ks = 0; ks < 2; ++ks)
#pragma unroll
            for (int j = 0; j < 8; ++j)
                w1a[jt][ks][j] = (f16)W1[(ks * 32 + q * 8 + j) * 256 + jt * 16 + c];

    f16x8 w2a[4][8];    // W2T hi
#pragma unroll
    for (int dt = 0; dt < 4; ++dt)
#pragma unroll
        for (int ks = 0; ks < 8; ++ks)
#pragma unroll
            for (int j = 0; j < 8; ++j)
                w2a[dt][ks][j] = (f16)W2[(ks * 32 + q * 8 + j) * 64 + dt * 16 + c];

    // ---------------- lo-weight A-fragments -> LDS (split across waves) ----------------
    for (int jt = wid * 4; jt < wid * 4 + 4; ++jt)
        for (int ks = 0; ks < 2; ++ks)
            for (int j = 0; j < 8; ++j) {
                float w = W1[(ks * 32 + q * 8 + j) * 256 + jt * 16 + c];
                f16 hi = (f16)w;
                w1loL[((jt * 2 + ks) * 64 + lane) * 8 + j] = (f16)(w - (float)hi);
            }
    {
        int dt = wid;
        for (int ks = 0; ks < 8; ++ks)
            for (int j = 0; j < 8; ++j) {
                float w = W2[(ks * 32 + q * 8 + j) * 64 + dt * 16 + c];
                f16 hi = (f16)w;
                w2loL[((dt * 8 + ks) * 64 + lane) * 8 + j] = (f16)(w - (float)hi);
            }
    }
    if (wid == 0)
        for (int ot = 0; ot < 2; ++ot)
            for (int ks = 0; ks < 2; ++ks)
                for (int j = 0; j < 8; ++j)
                    wfcL[((ot * 2 + ks) * 64 + lane) * 8 + j] =
                        (f16)Wfc[(ks * 32 + q * 8 + j) * 32 + ot * 16 + c];
    __syncthreads();   // the only real barrier: lo-weights become read-only after this

    // biases to registers
    f32x4 b1v[16], b2v[4], bfcv[2];
#pragma unroll
    for (int jt = 0; jt < 16; ++jt)
#pragma unroll
        for (int r = 0; r < 4; ++r) b1v[jt][r] = b1[jt * 16 + 4 * q + r];
#pragma unroll
    for (int dt = 0; dt < 4; ++dt)
#pragma unroll
        for (int r = 0; r < 4; ++r) b2v[dt][r] = b2[dt * 16 + 4 * q + r];
#pragma unroll
    for (int ot = 0; ot < 2; ++ot)
#pragma unroll
        for (int r = 0; r < 4; ++r) bfcv[ot][r] = bfc[ot * 16 + 4 * q + r];

    // ---------------- init from y0 (split hi+lo) ----------------
    f16x8 y0hi[2], y0lo[2];
#pragma unroll
    for (int ks = 0; ks < 2; ++ks)
#pragma unroll
        for (int j = 0; j < 8; ++j) {
            float v = y0g[(R0 + c) * 64 + ks * 32 + q * 8 + j];
            f16 hi = (f16)v;
            y0hi[ks][j] = hi;
            y0lo[ks][j] = (f16)(v - (float)hi);
        }

    f32x4 P1[16];
#pragma unroll
    for (int jt = 0; jt < 16; ++jt) {
        f32x4 cc = b1v[jt];
#pragma unroll
        for (int ks = 0; ks < 2; ++ks) {
            f16x8 alo = *reinterpret_cast<const f16x8*>(&w1loL[((jt * 2 + ks) * 64 + lane) * 8]);
            cc = MFMA(w1a[jt][ks], y0hi[ks], cc);
            cc = MFMA(w1a[jt][ks], y0lo[ks], cc);
            cc = MFMA(alo,         y0hi[ks], cc);
        }
        P1[jt] = cc;
    }
    f32x4 pfc[2];
#pragma unroll
    for (int ot = 0; ot < 2; ++ot) {
        f32x4 z = {0.f, 0.f, 0.f, 0.f};
#pragma unroll
        for (int ks = 0; ks < 2; ++ks) {
            f16x8 wa = *reinterpret_cast<const f16x8*>(&wfcL[((ot * 2 + ks) * 64 + lane) * 8]);
            z = MFMA(wa, y0hi[ks], z);
            z = MFMA(wa, y0lo[ks], z);
        }
        pfc[ot] = z;
    }
#pragma unroll
    for (int ot = 0; ot < 2; ++ot) {
        f32x4 v = pfc[ot] + bfcv[ot];
        *reinterpret_cast<f32x4*>(&out[(size_t)(R0 + c) * 32 + ot * 16 + 4 * q]) = v;
    }

    f32x4 U[16];
#pragma unroll
    for (int jt = 0; jt < 16; ++jt) U[jt] = f32x4{0.f, 0.f, 0.f, 0.f};
    f32x4 dy[4];
#pragma unroll
    for (int dt = 0; dt < 4; ++dt) dy[dt] = f32x4{0.f, 0.f, 0.f, 0.f};
    f32x4 S[16];

    float hh = 0.f, ch = 0.f, c6 = 0.f;

    auto stage = [&](float carg, float w, bool first) {
        // (1) h = tanh(P1 + carg*U): split hi/lo -> wave-private LDS
#pragma unroll
        for (int jt = 0; jt < 16; ++jt) {
            float a0 = P1[jt][0], a1 = P1[jt][1], a2 = P1[jt][2], a3 = P1[jt][3];
            if (!first) {
                a0 = __builtin_fmaf(carg, U[jt][0], a0);
                a1 = __builtin_fmaf(carg, U[jt][1], a1);
                a2 = __builtin_fmaf(carg, U[jt][2], a2);
                a3 = __builtin_fmaf(carg, U[jt][3], a3);
            }
            float t0 = fast_tanh(a0), t1 = fast_tanh(a1), t2 = fast_tanh(a2), t3 = fast_tanh(a3);
            f16x4 hv, lv;
            hv[0] = (f16)t0; hv[1] = (f16)t1; hv[2] = (f16)t2; hv[3] = (f16)t3;
            lv[0] = (f16)(t0 - (float)hv[0]); lv[1] = (f16)(t1 - (float)hv[1]);
            lv[2] = (f16)(t2 - (float)hv[2]); lv[3] = (f16)(t3 - (float)hv[3]);
            *reinterpret_cast<f16x4*>(&hhi[c * 264 + jt * 16 + 4 * q]) = hv;
            *reinterpret_cast<f16x4*>(&hlo[c * 264 + jt * 16 + 4 * q]) = lv;
        }
        wave_exchange_fence();
        // (2) kT = hhi@W2hi + hlo@W2hi + hhi@W2lo + b2
        f32x4 ka[4];
#pragma unroll
        for (int dt = 0; dt < 4; ++dt) ka[dt] = b2v[dt];
#pragma unroll
        for (int ks = 0; ks < 8; ++ks) {
            f16x8 bhi = *reinterpret_cast<const f16x8*>(&hhi[c * 264 + ks * 32 + q * 8]);
            f16x8 blo = *reinterpret_cast<const f16x8*>(&hlo[c * 264 + ks * 32 + q * 8]);
#pragma unroll
            for (int dt = 0; dt < 4; ++dt) {
                f16x8 alo = *reinterpret_cast<const f16x8*>(&w2loL[((dt * 8 + ks) * 64 + lane) * 8]);
                ka[dt] = MFMA(w2a[dt][ks], bhi, ka[dt]);
                ka[dt] = MFMA(w2a[dt][ks], blo, ka[dt]);
                ka[dt] = MFMA(alo,          bhi, ka[dt]);
            }
        }
        // (3) dy += (c6*w)*k ; split k hi/lo -> wave-private LDS
        float cw = c6 * w;
#pragma unroll
        for (int dt = 0; dt < 4; ++dt) {
            dy[dt] += ka[dt] * cw;
            f16x4 hv, lv;
            hv[0] = (f16)ka[dt][0]; hv[1] = (f16)ka[dt][1];
            hv[2] = (f16)ka[dt][2]; hv[3] = (f16)ka[dt][3];
            lv[0] = (f16)(ka[dt][0] - (float)hv[0]); lv[1] = (f16)(ka[dt][1] - (float)hv[1]);
            lv[2] = (f16)(ka[dt][2] - (float)hv[2]); lv[3] = (f16)(ka[dt][3] - (float)hv[3]);
            *reinterpret_cast<f16x4*>(&khi[c * 72 + dt * 16 + 4 * q]) = hv;
            *reinterpret_cast<f16x4*>(&klo[c * 72 + dt * 16 + 4 * q]) = lv;
        }
        wave_exchange_fence();
        // (4) UT = khi@W1hi + klo@W1hi + khi@W1lo
        f16x8 kh0 = *reinterpret_cast<const f16x8*>(&khi[c * 72 + q * 8]);
        f16x8 kh1 = *reinterpret_cast<const f16x8*>(&khi[c * 72 + 32 + q * 8]);
        f16x8 kl0 = *reinterpret_cast<const f16x8*>(&klo[c * 72 + q * 8]);
        f16x8 kl1 = *reinterpret_cast<const f16x8*>(&klo[c * 72 + 32 + q * 8]);
#pragma unroll
        for (int jt = 0; jt < 16; ++jt) {
            f16x8 a0 = *reinterpret_cast<const f16x8*>(&w1loL[((jt * 2 + 0) * 64 + lane) * 8]);
            f16x8 a1 = *reinterpret_cast<const f16x8*>(&w1loL[((jt * 2 + 1) * 64 + lane) * 8]);
            f32x4 z = {0.f, 0.f, 0.f, 0.f};
            z = MFMA(w1a[jt][0], kh0, z);
            z = MFMA(w1a[jt][0], kl0, z);
            z = MFMA(a0,         kh0, z);
            z = MFMA(w1a[jt][1], kh1, z);
            z = MFMA(w1a[jt][1], kl1, z);
            z = MFMA(a1,         kh1, z);
            U[jt] = z;
        }
        // (5) S += w * U
#pragma unroll
        for (int jt = 0; jt < 16; ++jt) S[jt] += U[jt] * w;
        __builtin_amdgcn_wave_barrier();  // order insurance: next stage rewrites h/k
    };

#pragma unroll 1
    for (int ti = 0; ti < 49; ++ti) {
        float dtv = tg[ti + 1] - tg[ti];
        hh = dtv * 0.125f;
        ch = 0.5f * hh;
        c6 = hh * (1.0f / 6.0f);
#pragma unroll 1
        for (int sub = 0; sub < 8; ++sub) {
#pragma unroll
            for (int jt = 0; jt < 16; ++jt) S[jt] = f32x4{0.f, 0.f, 0.f, 0.f};
            stage(0.0f, 1.0f, true);
            stage(ch,   2.0f, false);
            stage(ch,   2.0f, false);
            stage(hh,   1.0f, false);
#pragma unroll
            for (int jt = 0; jt < 16; ++jt) P1[jt] += S[jt] * c6;
        }
        // ---- interval epilogue: pfc += dy @ Wfc (dy split hi+lo), emit row ----
#pragma unroll
        for (int dt = 0; dt < 4; ++dt) {
            f16x4 hv, lv;
            hv[0] = (f16)dy[dt][0]; hv[1] = (f16)dy[dt][1];
            hv[2] = (f16)dy[dt][2]; hv[3] = (f16)dy[dt][3];
            lv[0] = (f16)(dy[dt][0] - (float)hv[0]); lv[1] = (f16)(dy[dt][1] - (float)hv[1]);
            lv[2] = (f16)(dy[dt][2] - (float)hv[2]); lv[3] = (f16)(dy[dt][3] - (float)hv[3]);
            *reinterpret_cast<f16x4*>(&khi[c * 72 + dt * 16 + 4 * q]) = hv;
            *reinterpret_cast<f16x4*>(&klo[c * 72 + dt * 16 + 4 * q]) = lv;
            dy[dt] = f32x4{0.f, 0.f, 0.f, 0.f};
        }
        wave_exchange_fence();
        {
            f16x8 dh0 = *reinterpret_cast<const f16x8*>(&khi[c * 72 + q * 8]);
            f16x8 dh1 = *reinterpret_cast<const f16x8*>(&khi[c * 72 + 32 + q * 8]);
            f16x8 dl0 = *reinterpret_cast<const f16x8*>(&klo[c * 72 + q * 8]);
            f16x8 dl1 = *reinterpret_cast<const f16x8*>(&klo[c * 72 + 32 + q * 8]);
#pragma unroll
            for (int ot = 0; ot < 2; ++ot) {
                f16x8 wa0 = *reinterpret_cast<const f16x8*>(&wfcL[((ot * 2 + 0) * 64 + lane) * 8]);
                f16x8 wa1 = *reinterpret_cast<const f16x8*>(&wfcL[((ot * 2 + 1) * 64 + lane) * 8]);
                pfc[ot] = MFMA(wa0, dh0, pfc[ot]);
                pfc[ot] = MFMA(wa0, dl0, pfc[ot]);
                pfc[ot] = MFMA(wa1, dh1, pfc[ot]);
                pfc[ot] = MFMA(wa1, dl1, pfc[ot]);
            }
        }
        __builtin_amdgcn_wave_barrier();  // next interval rewrites khi/klo
        size_t base = (size_t)(ti + 1) * (16384 * 32);
#pragma unroll
        for (int ot = 0; ot < 2; ++ot) {
            f32x4 v = pfc[ot] + bfcv[ot];
            *reinterpret_cast<f32x4*>(&out[base + (size_t)(R0 + c) * 32 + ot * 16 + 4 * q]) = v;
        }
    }
}

extern "C" void kernel_launch(void* const* d_in, const int* in_sizes, int n_in,
                              void* d_out, int out_size, void* d_ws, size_t ws_size,
                              hipStream_t stream) {
    (void)in_sizes; (void)n_in; (void)d_ws; (void)ws_size; (void)out_size;
    const float* y0  = (const float*)d_in[0];
    const float* t   = (const float*)d_in[1];
    const float* W1  = (const float*)d_in[2];
    const float* b1  = (const float*)d_in[3];
    const float* W2  = (const float*)d_in[4];
    const float* b2  = (const float*)d_in[5];
    const float* Wfc = (const float*)d_in[6];
    const float* bfc = (const float*)d_in[7];
    float* out = (float*)d_out;
    // 256 blocks x 256 threads: 4 waves x 16 rows per block, 1 block/CU (152 KB LDS)
    node_fused<<<dim3(256), dim3(256), 0, stream>>>(y0, t, W1, b1, W2, b2, Wfc, bfc, out);
}